// Round 1
// baseline (324.567 us; speedup 1.0000x reference)
//
#include <hip/hip_runtime.h>

// LengthRegulator: B=32, T_src=1024, H=512 fixed by the problem.
// d_out layout: [expanded (B*max_len*H) f32][mel_masks (B*max_len) f32(0/1)]
// max_len is recovered from out_size = B*max_len*(H+1).

#define B_SZ   32
#define T_SRC  1024
#define H_DIM  512

// One block per batch row: inclusive scan of durations into ws (cum).
__global__ void __launch_bounds__(T_SRC) lr_scan_kernel(const int* __restrict__ dur,
                                                        int* __restrict__ cum) {
    __shared__ int s[T_SRC];
    const int b   = blockIdx.x;
    const int tid = threadIdx.x;
    s[tid] = dur[b * T_SRC + tid];
    __syncthreads();
#pragma unroll
    for (int off = 1; off < T_SRC; off <<= 1) {
        int v = (tid >= off) ? s[tid - off] : 0;
        __syncthreads();
        s[tid] += v;
        __syncthreads();
    }
    cum[b * T_SRC + tid] = s[tid];
}

// One 128-thread block per output frame (b, t): binary-search the cum row
// (block-uniform → no divergence, probes broadcast from L1), then float4-copy
// the 2 KB source frame. Padded frames write zeros + mask=1.
__global__ void __launch_bounds__(128) lr_expand_kernel(const float* __restrict__ x,
                                                        const int* __restrict__ cum,
                                                        float* __restrict__ out,
                                                        float* __restrict__ mask,
                                                        int max_len) {
    const int t   = blockIdx.x;
    const int b   = blockIdx.y;
    const int tid = threadIdx.x;

    const int* c    = cum + b * T_SRC;
    const int total = c[T_SRC - 1];

    float4* out4 = (float4*)(out + ((size_t)b * max_len + t) * H_DIM);

    if (t >= total) {
        if (tid == 0) mask[(size_t)b * max_len + t] = 1.0f;
        out4[tid] = make_float4(0.f, 0.f, 0.f, 0.f);
        return;
    }
    if (tid == 0) mask[(size_t)b * max_len + t] = 0.0f;

    // idx = #{i : c[i] <= t}  ==  searchsorted(c, t, side='right').
    // t < total = c[1023] guarantees idx <= 1023 (no clip needed).
    int idx = 0;
#pragma unroll
    for (int sh = 9; sh >= 0; --sh) {
        int probe = idx + (1 << sh);
        if (c[probe - 1] <= t) idx = probe;
    }

    const float4* src4 = (const float4*)(x + ((size_t)b * T_SRC + idx) * H_DIM);
    out4[tid] = src4[tid];
}

extern "C" void kernel_launch(void* const* d_in, const int* in_sizes, int n_in,
                              void* d_out, int out_size, void* d_ws, size_t ws_size,
                              hipStream_t stream) {
    const float* x   = (const float*)d_in[0];
    const int*   dur = (const int*)d_in[1];
    float*       out = (float*)d_out;
    int*         cum = (int*)d_ws;   // B_SZ * T_SRC ints = 128 KB

    const int max_len = out_size / (B_SZ * (H_DIM + 1));
    float* mask = out + (size_t)B_SZ * max_len * H_DIM;

    lr_scan_kernel<<<B_SZ, T_SRC, 0, stream>>>(dur, cum);

    dim3 grid(max_len, B_SZ);
    lr_expand_kernel<<<grid, 128, 0, stream>>>(x, cum, out, mask, max_len);
}

// Round 2
// 319.551 us; speedup vs baseline: 1.0157x; 1.0157x over previous
//
#include <hip/hip_runtime.h>

// LengthRegulator: B=32, T_src=1024, H=512 fixed by the problem.
// d_out layout: [expanded (B*max_len*H) f32][mel_masks (B*max_len) f32(0/1)]
// max_len recovered from out_size = B*max_len*(H+1).
//
// Strategy: scan -> scatter (each source frame writes its own output range
// [cum[s-1], cum[s]) -- no per-output binary search, no dependent-load chains)
// -> pad pass zeroing t >= total and writing the mask.

#define B_SZ   32
#define T_SRC  1024
#define H_DIM  512

// One block per batch row: inclusive scan of durations into ws (cum).
__global__ void __launch_bounds__(T_SRC) lr_scan_kernel(const int* __restrict__ dur,
                                                        int* __restrict__ cum) {
    __shared__ int s[T_SRC];
    const int b   = blockIdx.x;
    const int tid = threadIdx.x;
    s[tid] = dur[b * T_SRC + tid];
    __syncthreads();
#pragma unroll
    for (int off = 1; off < T_SRC; off <<= 1) {
        int v = (tid >= off) ? s[tid - off] : 0;
        __syncthreads();
        s[tid] += v;
        __syncthreads();
    }
    cum[b * T_SRC + tid] = s[tid];
}

// One 128-thread block per SOURCE frame (s, b): load x[b,s] (float4/lane)
// once, store it to output rows [start, end). Stores are independent ->
// pure write bandwidth. dur==0 frames exit immediately.
__global__ void __launch_bounds__(128) lr_scatter_kernel(const float* __restrict__ x,
                                                         const int* __restrict__ cum,
                                                         float* __restrict__ out,
                                                         float* __restrict__ mask,
                                                         int max_len) {
    const int s   = blockIdx.x;
    const int b   = blockIdx.y;
    const int tid = threadIdx.x;

    const int* c    = cum + b * T_SRC;
    const int end   = c[s];
    const int start = (s == 0) ? 0 : c[s - 1];
    if (start == end) return;

    const float4 v = ((const float4*)(x + ((size_t)b * T_SRC + s) * H_DIM))[tid];
    float* maskb = mask + (size_t)b * max_len;

    for (int t = start; t < end; ++t) {
        ((float4*)(out + ((size_t)b * max_len + t) * H_DIM))[tid] = v;
        if (tid == 0) maskb[t] = 0.0f;
    }
}

// One 128-thread block per output frame (t, b): zero + mask=1 for the padded
// tail t >= total; early-exit (single L1-hit broadcast load) otherwise.
__global__ void __launch_bounds__(128) lr_pad_kernel(const int* __restrict__ cum,
                                                     float* __restrict__ out,
                                                     float* __restrict__ mask,
                                                     int max_len) {
    const int t     = blockIdx.x;
    const int b     = blockIdx.y;
    const int total = cum[b * T_SRC + T_SRC - 1];
    if (t < total) return;

    ((float4*)(out + ((size_t)b * max_len + t) * H_DIM))[threadIdx.x] =
        make_float4(0.f, 0.f, 0.f, 0.f);
    if (threadIdx.x == 0) mask[(size_t)b * max_len + t] = 1.0f;
}

extern "C" void kernel_launch(void* const* d_in, const int* in_sizes, int n_in,
                              void* d_out, int out_size, void* d_ws, size_t ws_size,
                              hipStream_t stream) {
    const float* x   = (const float*)d_in[0];
    const int*   dur = (const int*)d_in[1];
    float*       out = (float*)d_out;
    int*         cum = (int*)d_ws;   // B_SZ * T_SRC ints = 128 KB

    const int max_len = out_size / (B_SZ * (H_DIM + 1));
    float* mask = out + (size_t)B_SZ * max_len * H_DIM;

    lr_scan_kernel<<<B_SZ, T_SRC, 0, stream>>>(dur, cum);

    dim3 sgrid(T_SRC, B_SZ);
    lr_scatter_kernel<<<sgrid, 128, 0, stream>>>(x, cum, out, mask, max_len);

    dim3 pgrid(max_len, B_SZ);
    lr_pad_kernel<<<pgrid, 128, 0, stream>>>(cum, out, mask, max_len);
}

// Round 3
// 304.166 us; speedup vs baseline: 1.0671x; 1.0506x over previous
//
#include <hip/hip_runtime.h>

// LengthRegulator: B=32, T_src=1024, H=512 fixed by the problem.
// d_out layout: [expanded (B*max_len*H) f32][mel_masks (B*max_len) f32(0/1)]
// max_len recovered from out_size = B*max_len*(H+1).
//
// R3: single fused expand kernel. Each 256-thread block stages the cum row in
// LDS, computes 16 searchsorted indices in parallel (LDS probes), then copies
// 16 output rows (incl. zero-fill for padded tail + mask) with float4 stores.

#define B_SZ   32
#define T_SRC  1024
#define H_DIM  512
#define ROWS   16      // output rows per block

// One block per batch row: inclusive scan of durations into ws (cum).
__global__ void __launch_bounds__(T_SRC) lr_scan_kernel(const int* __restrict__ dur,
                                                        int* __restrict__ cum) {
    __shared__ int s[T_SRC];
    const int b   = blockIdx.x;
    const int tid = threadIdx.x;
    s[tid] = dur[b * T_SRC + tid];
    __syncthreads();
#pragma unroll
    for (int off = 1; off < T_SRC; off <<= 1) {
        int v = (tid >= off) ? s[tid - off] : 0;
        __syncthreads();
        s[tid] += v;
        __syncthreads();
    }
    cum[b * T_SRC + tid] = s[tid];
}

__global__ void __launch_bounds__(256) lr_expand_fused(const float* __restrict__ x,
                                                       const int* __restrict__ cum,
                                                       float* __restrict__ out,
                                                       float* __restrict__ mask,
                                                       int max_len) {
    __shared__ int c[T_SRC];
    __shared__ int sidx[ROWS];

    const int b   = blockIdx.y;
    const int t0  = blockIdx.x * ROWS;
    const int tid = threadIdx.x;

    // Stage cum row in LDS (4 KB, coalesced, L2-hit after first block).
    const int* crow = cum + b * T_SRC;
#pragma unroll
    for (int i = tid; i < T_SRC; i += 256) c[i] = crow[i];
    __syncthreads();

    const int total = c[T_SRC - 1];

    // 16 parallel binary searches (one thread per output row of this block).
    if (tid < ROWS) {
        const int t = t0 + tid;
        int idx = 0;
#pragma unroll
        for (int sh = 9; sh >= 0; --sh) {
            int probe = idx + (1 << sh);
            if (c[probe - 1] <= t) idx = probe;
        }
        sidx[tid] = (t < total) ? idx : -1;   // -1 marks padded row
        if (t < max_len)
            mask[(size_t)b * max_len + t] = (t < total) ? 0.0f : 1.0f;
    }
    __syncthreads();

    // Copy rows: 256 threads = 2 rows per iteration (128 float4 lanes/row).
    const int rlane = tid & 127;
    const int rsel  = tid >> 7;
    for (int r = rsel; r < ROWS; r += 2) {
        const int t = t0 + r;
        if (t >= max_len) break;               // monotone in r
        const int idx = sidx[r];
        float4 v = (idx >= 0)
            ? ((const float4*)(x + ((size_t)b * T_SRC + idx) * H_DIM))[rlane]
            : make_float4(0.f, 0.f, 0.f, 0.f);
        ((float4*)(out + ((size_t)b * max_len + t) * H_DIM))[rlane] = v;
    }
}

extern "C" void kernel_launch(void* const* d_in, const int* in_sizes, int n_in,
                              void* d_out, int out_size, void* d_ws, size_t ws_size,
                              hipStream_t stream) {
    const float* x   = (const float*)d_in[0];
    const int*   dur = (const int*)d_in[1];
    float*       out = (float*)d_out;
    int*         cum = (int*)d_ws;   // B_SZ * T_SRC ints = 128 KB

    const int max_len = out_size / (B_SZ * (H_DIM + 1));
    float* mask = out + (size_t)B_SZ * max_len * H_DIM;

    lr_scan_kernel<<<B_SZ, T_SRC, 0, stream>>>(dur, cum);

    dim3 grid((max_len + ROWS - 1) / ROWS, B_SZ);
    lr_expand_fused<<<grid, 256, 0, stream>>>(x, cum, out, mask, max_len);
}

// Round 4
// 300.515 us; speedup vs baseline: 1.0800x; 1.0122x over previous
//
#include <hip/hip_runtime.h>

// LengthRegulator: B=32, T_src=1024, H=512 fixed by the problem.
// d_out layout: [expanded (B*max_len*H) f32][mel_masks (B*max_len) f32(0/1)]
// max_len recovered from out_size = B*max_len*(H+1).
//
// R4: two passes.
//   A) per-batch scan + idx-map scatter (idx[b][t] = source frame, -1 = pad)
//      + mask write. No binary searches anywhere.
//   B) streaming copy: one wave per output row, grid-stride, no LDS, no
//      barriers -- pure store bandwidth.

#define B_SZ   32
#define T_SRC  1024
#define H_DIM  512

__global__ void __launch_bounds__(T_SRC) lr_prep(const int* __restrict__ dur,
                                                 int* __restrict__ idxbuf,
                                                 float* __restrict__ mask,
                                                 int max_len) {
    __shared__ int s[T_SRC];
    const int b   = blockIdx.x;
    const int tid = threadIdx.x;
    s[tid] = dur[b * T_SRC + tid];
    __syncthreads();
#pragma unroll
    for (int off = 1; off < T_SRC; off <<= 1) {
        int v = (tid >= off) ? s[tid - off] : 0;
        __syncthreads();
        s[tid] += v;
        __syncthreads();
    }
    const int end   = s[tid];
    const int start = tid ? s[tid - 1] : 0;
    const int total = s[T_SRC - 1];

    // Scatter: for t in [cum[s-1], cum[s]), searchsorted(cum,t,'right') == tid.
    int* ib = idxbuf + (size_t)b * max_len;
    for (int t = start; t < end; ++t) ib[t] = tid;
    // Padded tail.
    for (int t = total + tid; t < max_len; t += T_SRC) ib[t] = -1;
    // Mask.
    float* mb = mask + (size_t)b * max_len;
    for (int t = tid; t < max_len; t += T_SRC) mb[t] = (t < total) ? 0.0f : 1.0f;
}

// One wave per output row, grid-stride over rows of batch b = blockIdx.y.
// Each lane moves 2 float4s (2 KB/row total). idx load is wave-uniform
// (broadcast, L2-resident 460 KB).
__global__ void __launch_bounds__(256) lr_copy(const float* __restrict__ x,
                                               const int* __restrict__ idxbuf,
                                               float* __restrict__ out,
                                               int max_len, int nwaves_x) {
    const int b    = blockIdx.y;
    const int lane = threadIdx.x & 63;
    const int wv   = (blockIdx.x << 2) | (threadIdx.x >> 6);

    const int*   ib = idxbuf + (size_t)b * max_len;
    const float* xb = x      + (size_t)b * T_SRC   * H_DIM;
    float*       ob = out    + (size_t)b * max_len * H_DIM;

    for (int t = wv; t < max_len; t += nwaves_x) {
        const int sidx = ib[t];
        float4 v0 = make_float4(0.f, 0.f, 0.f, 0.f), v1 = v0;
        if (sidx >= 0) {
            const float4* src = (const float4*)(xb + (size_t)sidx * H_DIM);
            v0 = src[lane];
            v1 = src[lane + 64];
        }
        float4* dst = (float4*)(ob + (size_t)t * H_DIM);
        dst[lane]      = v0;
        dst[lane + 64] = v1;
    }
}

extern "C" void kernel_launch(void* const* d_in, const int* in_sizes, int n_in,
                              void* d_out, int out_size, void* d_ws, size_t ws_size,
                              hipStream_t stream) {
    const float* x   = (const float*)d_in[0];
    const int*   dur = (const int*)d_in[1];
    float*       out = (float*)d_out;
    int*         idxbuf = (int*)d_ws;   // B_SZ * max_len ints (~460 KB)

    const int max_len = out_size / (B_SZ * (H_DIM + 1));
    float* mask = out + (size_t)B_SZ * max_len * H_DIM;

    lr_prep<<<B_SZ, T_SRC, 0, stream>>>(dur, idxbuf, mask, max_len);

    const int gx = 64;                        // 64 blocks x 4 waves = 256 waves per batch row
    dim3 grid(gx, B_SZ);
    lr_copy<<<grid, 256, 0, stream>>>(x, idxbuf, out, max_len, gx * 4);
}